// Round 1
// baseline (632.532 us; speedup 1.0000x reference)
//
#include <hip/hip_runtime.h>
#include <hip/hip_fp16.h>
#include <stdint.h>
#include <math.h>

typedef _Float16 f16;
typedef _Float16 f16x8 __attribute__((ext_vector_type(8)));
typedef float f32x4 __attribute__((ext_vector_type(4)));

#define DIM_   1024
#define STATE_ 16
#define INNER_ 2048
#define BATCH_ 4
#define LSEQ_  2048
#define NROWS_ (BATCH_*LSEQ_)   /* 8192 */
#define SEG_   16
#define SEGLEN_ 128

// ---------------------------------------------------------------- utilities
__device__ __forceinline__ void gl_lds16(const void* g, void* l) {
  __builtin_amdgcn_global_load_lds(
      (const __attribute__((address_space(1))) uint32_t*)g,
      (__attribute__((address_space(3))) uint32_t*)l,
      16, 0, 0);
}

__global__ void cvt16(const float* __restrict__ in, f16* __restrict__ out, int n) {
  int i = blockIdx.x * 256 + threadIdx.x;
  int stride = gridDim.x * 256;
  for (; i < n; i += stride) out[i] = (f16)in[i];
}

__global__ void fillz16(f16* __restrict__ out, int n) {
  int i = blockIdx.x * 256 + threadIdx.x;
  int stride = gridDim.x * 256;
  for (; i < n; i += stride) out[i] = (f16)0.f;
}

// ---------------------------------------------------------------- GEMM
// C[M,N] = A[M,K] @ B[N,K]^T, fp16 inputs, fp32 accumulate (MFMA 16x16x32).
// 128x128 tile, BK=32, 4 waves (2x2), each wave 64x64 (4x4 fragments).
// MODE 0: in_proj epilogue -> out0 = x_in fp32 [M,2048], out1 = silu(res) f16 [M,2048]
// MODE 1: dt epilogue      -> out0 = softplus(v+bias) fp32 [M,2048],
//                             out0b = Bm/Cm fp32 [M,32] (cols 2048..2079), cols>=2080 dropped
// MODE 2: plain fp32 store -> out0 [M,N]
template<int MODE>
__global__ __launch_bounds__(256)
void gemm16(const f16* __restrict__ A, const f16* __restrict__ B,
            int M, int N, int K,
            float* __restrict__ out0, float* __restrict__ out0b,
            f16* __restrict__ out1, const float* __restrict__ bias)
{
  __shared__ __align__(16) f16 As[128*32];
  __shared__ __align__(16) f16 Bs[128*32];

  const int tid  = threadIdx.x;
  const int lane = tid & 63;
  const int wave = tid >> 6;          // 0..3
  const int wr   = wave >> 1;         // wave row (0..1)
  const int wc   = wave & 1;          // wave col (0..1)
  const int bm   = blockIdx.y * 128;
  const int bn   = blockIdx.x * 128;

  // staging: each wave stages 32 rows of A and 32 rows of B per K-step,
  // as 2 issues of 16 rows (64 lanes x 16B = 1KB = 16 rows x 64B).
  const int srow  = lane >> 2;        // 0..15
  const int skoff = (lane & 3) * 8;   // f16 elements
  const f16* Ag = A + (size_t)(bm + wave*32 + srow) * K + skoff;
  const f16* Bg = B + (size_t)(bn + wave*32 + srow) * K + skoff;
  f16* As0 = &As[(wave*32     )*32];
  f16* As1 = &As[(wave*32 + 16)*32];
  f16* Bs0 = &Bs[(wave*32     )*32];
  f16* Bs1 = &Bs[(wave*32 + 16)*32];

  const int lr = lane & 15;           // fragment row/col
  const int lk = lane >> 4;           // fragment k-group

  f32x4 acc[4][4] = {};

  for (int k0 = 0; k0 < K; k0 += 32) {
    gl_lds16(Ag,                 As0);
    gl_lds16(Ag + (size_t)16*K,  As1);
    gl_lds16(Bg,                 Bs0);
    gl_lds16(Bg + (size_t)16*K,  Bs1);
    Ag += 32; Bg += 32;
    __syncthreads();   // drains vmcnt -> staged tile visible

    f16x8 av[4], bv[4];
#pragma unroll
    for (int m = 0; m < 4; ++m)
      av[m] = *(const f16x8*)&As[(wr*64 + m*16 + lr)*32 + lk*8];
#pragma unroll
    for (int n = 0; n < 4; ++n)
      bv[n] = *(const f16x8*)&Bs[(wc*64 + n*16 + lr)*32 + lk*8];
#pragma unroll
    for (int m = 0; m < 4; ++m)
#pragma unroll
      for (int n = 0; n < 4; ++n)
        acc[m][n] = __builtin_amdgcn_mfma_f32_16x16x32_f16(av[m], bv[n], acc[m][n], 0, 0, 0);
    __syncthreads();   // all waves done reading before next stage
  }

  // epilogue: C/D layout col = lane&15, row = (lane>>4)*4 + i
  const int row0 = bm + wr*64 + (lane >> 4) * 4;
  const int col0 = bn + wc*64 + (lane & 15);
#pragma unroll
  for (int m = 0; m < 4; ++m) {
#pragma unroll
    for (int n = 0; n < 4; ++n) {
      const int c = col0 + n*16;
#pragma unroll
      for (int i = 0; i < 4; ++i) {
        const int r = row0 + m*16 + i;
        const float v = acc[m][n][i];
        if (MODE == 0) {
          const int half = N >> 1;
          if (c < half) {
            out0[(size_t)r*half + c] = v;
          } else {
            float sg = 1.f / (1.f + __expf(-v));
            out1[(size_t)r*half + (c - half)] = (f16)(v * sg);
          }
        } else if (MODE == 1) {
          if (c < 2048) {
            float t = v + bias[c];
            out0[(size_t)r*2048 + c] = (t > 15.f) ? t : log1pf(__expf(t));
          } else if (c < 2080) {
            out0b[(size_t)r*32 + (c - 2048)] = v;
          }
        } else {
          out0[(size_t)r*N + c] = v;
        }
      }
    }
  }
}

// ---------------------------------------------------------------- conv+silu
// x_in fp32 [8192,2048] -> xc f16 [8192,2048]; causal depthwise conv k=4 + silu
__global__ __launch_bounds__(256)
void conv_silu(const float* __restrict__ xin, const float* __restrict__ cw,
               const float* __restrict__ cb, f16* __restrict__ xc)
{
  size_t idx = (size_t)blockIdx.x * 256 + threadIdx.x;   // over NROWS_*INNER_
  const int d = (int)(idx & (INNER_ - 1));
  const int r = (int)(idx >> 11);
  const int t = r & (LSEQ_ - 1);
  float acc = cb[d];
#pragma unroll
  for (int k = 0; k < 4; ++k) {
    int tt = t + k - 3;
    if (tt >= 0)
      acc += cw[d*4 + k] * xin[((size_t)(r + k - 3))*INNER_ + d];
  }
  float sg = 1.f / (1.f + __expf(-acc));
  xc[idx] = (f16)(acc * sg);
}

// ---------------------------------------------------------------- scan
// pass 1: per-segment local scan from zero init; save final state + sum(dt)
__global__ __launch_bounds__(256)
void scan_local(const float* __restrict__ dt, const f16* __restrict__ xc,
                const float* __restrict__ bc32, const float* __restrict__ alog,
                float* __restrict__ Q, float* __restrict__ DTS)
{
  const int tid = threadIdx.x;
  const int b = blockIdx.z, seg = blockIdx.y, dc = blockIdx.x;
  const int d = dc*256 + tid;
  const int r0 = b*LSEQ_ + seg*SEGLEN_;

  __shared__ float bs[SEGLEN_][16];
  for (int i = tid; i < SEGLEN_*16; i += 256)
    bs[i >> 4][i & 15] = bc32[(size_t)(r0 + (i >> 4))*32 + (i & 15)];

  float Ac[16];
#pragma unroll
  for (int s = 0; s < 16; ++s) Ac[s] = -__expf(alog[d*16 + s]);
  __syncthreads();

  float st[16];
#pragma unroll
  for (int s = 0; s < 16; ++s) st[s] = 0.f;
  float dtsum = 0.f;

  for (int tt = 0; tt < SEGLEN_; ++tt) {
    const size_t idx = (size_t)(r0 + tt)*INNER_ + d;
    const float dtv = dt[idx];
    const float xv  = (float)xc[idx];
    const float dtx = dtv * xv;
    dtsum += dtv;
#pragma unroll
    for (int s = 0; s < 16; ++s) {
      float ab = __expf(Ac[s]*dtv);
      st[s] = fmaf(ab, st[s], dtx * bs[tt][s]);
    }
  }
  const size_t qb = ((size_t)(b*INNER_ + d)*SEG_ + seg)*16;
#pragma unroll
  for (int s = 0; s < 16; ++s) Q[qb + s] = st[s];
  DTS[(size_t)(b*INNER_ + d)*SEG_ + seg] = dtsum;
}

// pass 2: segment-level scan -> initial state per segment
__global__ __launch_bounds__(256)
void scan_fix(const float* __restrict__ alog, const float* __restrict__ DTS,
              const float* __restrict__ Q, float* __restrict__ INIT)
{
  const int idx = blockIdx.x*256 + threadIdx.x;   // (b*INNER+d)*16+s, 131072 total
  const int s = idx & 15;
  const int bd = idx >> 4;
  const int d = bd & (INNER_ - 1);
  const float A = -__expf(alog[d*16 + s]);
  float st = 0.f;
  for (int seg = 0; seg < SEG_; ++seg) {
    const size_t base = ((size_t)bd*SEG_ + seg)*16 + s;
    INIT[base] = st;
    const float dts = DTS[(size_t)bd*SEG_ + seg];
    st = __expf(A*dts)*st + Q[base];   // P = exp(A*sum(dt)) = prod A_bar
  }
}

// pass 3: recompute with correct init, emit y_t * silu(res) as f16
__global__ __launch_bounds__(256)
void scan_final(const float* __restrict__ dt, const f16* __restrict__ xc,
                const float* __restrict__ bc32, const float* __restrict__ alog,
                const float* __restrict__ INIT, const f16* __restrict__ res,
                f16* __restrict__ y16)
{
  const int tid = threadIdx.x;
  const int b = blockIdx.z, seg = blockIdx.y, dc = blockIdx.x;
  const int d = dc*256 + tid;
  const int r0 = b*LSEQ_ + seg*SEGLEN_;

  __shared__ float bs[SEGLEN_][32];
  for (int i = tid; i < SEGLEN_*32; i += 256)
    bs[i >> 5][i & 31] = bc32[(size_t)(r0 + (i >> 5))*32 + (i & 31)];

  float Ac[16];
#pragma unroll
  for (int s = 0; s < 16; ++s) Ac[s] = -__expf(alog[d*16 + s]);

  float st[16];
  const size_t ib = ((size_t)(b*INNER_ + d)*SEG_ + seg)*16;
#pragma unroll
  for (int s = 0; s < 16; ++s) st[s] = INIT[ib + s];
  __syncthreads();

  for (int tt = 0; tt < SEGLEN_; ++tt) {
    const size_t idx = (size_t)(r0 + tt)*INNER_ + d;
    const float dtv = dt[idx];
    const float xv  = (float)xc[idx];
    const float dtx = dtv * xv;
    float y = 0.f;
#pragma unroll
    for (int s = 0; s < 16; ++s) {
      float ab = __expf(Ac[s]*dtv);
      st[s] = fmaf(ab, st[s], dtx * bs[tt][s]);
      y = fmaf(st[s], bs[tt][16 + s], y);
    }
    y16[idx] = (f16)(y * (float)res[idx]);
  }
}

// ---------------------------------------------------------------- launch
extern "C" void kernel_launch(void* const* d_in, const int* in_sizes, int n_in,
                              void* d_out, int out_size, void* d_ws, size_t ws_size,
                              hipStream_t stream)
{
  const float* x    = (const float*)d_in[0];
  const float* w1   = (const float*)d_in[1];
  const float* cw   = (const float*)d_in[2];
  const float* cb   = (const float*)d_in[3];
  const float* dtw  = (const float*)d_in[4];
  const float* dtb  = (const float*)d_in[5];
  const float* alog = (const float*)d_in[6];
  const float* bw   = (const float*)d_in[7];
  const float* cwt  = (const float*)d_in[8];
  const float* ow   = (const float*)d_in[9];
  float* out = (float*)d_out;

  char* ws = (char*)d_ws;
  // workspace layout (bytes), total ~224.4 MB
  f16*   X16   = (f16*)  (ws + 0);          // 8192x1024 f16   = 16777216
  f16*   W1_16 = (f16*)  (ws + 16777216);   // 4096x1024 f16   =  8388608
  f16*   W2_16 = (f16*)  (ws + 25165824);   // 2176x2048 f16   =  8912896
  f16*   OW16  = (f16*)  (ws + 34078720);   // 1024x2048 f16   =  4194304
  f16*   RES16 = (f16*)  (ws + 38273024);   // 8192x2048 f16   = 33554432 (silu(res))
  f16*   XC16  = (f16*)  (ws + 71827456);   // 8192x2048 f16   = 33554432
  float* XIN32 = (float*)(ws + 105381888);  // 8192x2048 f32   = 67108864
  float* DT32  = XIN32;                     // aliased: XIN32 dead after conv
  float* BC32  = (float*)(ws + 172490752);  // 8192x32 f32     =  1048576
  float* DTS   = (float*)(ws + 173539328);  // 8192x16 f32     =   524288
  float* Q     = (float*)(ws + 174063616);  // 8192x16x16 f32  =  8388608
  float* INIT  = (float*)(ws + 182452224);  // 8192x16x16 f32  =  8388608
  f16*   Y16   = (f16*)  (ws + 190840832);  // 8192x2048 f16   = 33554432

  // fp32 -> fp16 conversions (weights + x); dt_w/B_w/C_w packed into W2_16 rows
  cvt16<<<2048, 256, 0, stream>>>(x,   X16,   NROWS_*DIM_);
  cvt16<<<2048, 256, 0, stream>>>(w1,  W1_16, 2*INNER_*DIM_);
  cvt16<<<2048, 256, 0, stream>>>(dtw, W2_16, INNER_*INNER_);
  cvt16<<<64,   256, 0, stream>>>(bw,  W2_16 + (size_t)2048*2048, STATE_*INNER_);
  cvt16<<<64,   256, 0, stream>>>(cwt, W2_16 + (size_t)2064*2048, STATE_*INNER_);
  fillz16<<<768, 256, 0, stream>>>(W2_16 + (size_t)2080*2048, 96*2048);
  cvt16<<<2048, 256, 0, stream>>>(ow,  OW16,  DIM_*INNER_);

  // GEMM1: xr = x @ in_proj_w^T -> x_in fp32, silu(res) f16
  gemm16<0><<<dim3(32, 64), 256, 0, stream>>>(X16, W1_16, NROWS_, 4096, 1024,
                                              XIN32, nullptr, RES16, nullptr);
  // depthwise conv + silu
  conv_silu<<<65536, 256, 0, stream>>>(XIN32, cw, cb, XC16);
  // GEMM2: dt_raw (+bias, softplus) and Bm/Cm (extra 32 cols)
  gemm16<1><<<dim3(17, 64), 256, 0, stream>>>(XC16, W2_16, NROWS_, 2176, 2048,
                                              DT32, BC32, nullptr, dtb);
  // segmented selective scan
  scan_local<<<dim3(8, SEG_, BATCH_), 256, 0, stream>>>(DT32, XC16, BC32, alog, Q, DTS);
  scan_fix  <<<512, 256, 0, stream>>>(alog, DTS, Q, INIT);
  scan_final<<<dim3(8, SEG_, BATCH_), 256, 0, stream>>>(DT32, XC16, BC32, alog, INIT, RES16, Y16);
  // GEMM3: out = (y * silu(res)) @ out_w^T
  gemm16<2><<<dim3(8, 64), 256, 0, stream>>>(Y16, OW16, NROWS_, 1024, 2048,
                                             out, nullptr, nullptr, nullptr);
}

// Round 2
// 586.012 us; speedup vs baseline: 1.0794x; 1.0794x over previous
//
#include <hip/hip_runtime.h>
#include <hip/hip_fp16.h>
#include <stdint.h>
#include <math.h>

typedef _Float16 f16;
typedef _Float16 f16x8 __attribute__((ext_vector_type(8)));
typedef float f32x4 __attribute__((ext_vector_type(4)));

#define DIM_   1024
#define STATE_ 16
#define INNER_ 2048
#define BATCH_ 4
#define LSEQ_  2048
#define NROWS_ 8192
#define SEG_   16
#define SEGLEN_ 128

// ---------------------------------------------------------------- utilities
__device__ __forceinline__ void gl_lds16(const void* g, void* l) {
  __builtin_amdgcn_global_load_lds(
      (const __attribute__((address_space(1))) uint32_t*)g,
      (__attribute__((address_space(3))) uint32_t*)l,
      16, 0, 0);
}

__global__ void cvt16(const float* __restrict__ in, f16* __restrict__ out, int n) {
  int i = blockIdx.x * 256 + threadIdx.x;
  int stride = gridDim.x * 256;
  for (; i < n; i += stride) out[i] = (f16)in[i];
}

__global__ void fillz16(f16* __restrict__ out, int n) {
  int i = blockIdx.x * 256 + threadIdx.x;
  int stride = gridDim.x * 256;
  for (; i < n; i += stride) out[i] = (f16)0.f;
}

// ---------------------------------------------------------------- GEMM (256^2, 8-phase)
// C[M,N] = A[M,K] @ B[N,K]^T, fp16 in, fp32 acc. 256x256 tile, BK=64, 8 waves (2Mx4N),
// per-wave out 128x64 (8x4 frags of 16x16x32). Double-buffered LDS (128KB), counted
// vmcnt(4) once per K-tile, XOR chunk swizzle (pre-swizzled global source), setprio.
// MODE 0: out0 = x_in fp32 [M,2048] (cols<2048), out1 = silu(res) f16 (cols>=2048)
// MODE 1: out0 = softplus(v+bias) fp32 (cols<2048), out0b = Bm/Cm fp32 [M,32]
//         (cols 2048..2079), cols>=2080 dropped (zero-padded B rows)
// MODE 2: plain fp32 store
template<int MODE>
__global__ __launch_bounds__(512, 2)
void gemm8p(const f16* __restrict__ A, const f16* __restrict__ B,
            int M, int N, int K,
            float* __restrict__ out0, float* __restrict__ out0b,
            f16* __restrict__ out1, const float* __restrict__ bias)
{
  __shared__ __align__(16) f16 Ab[2][256*64];
  __shared__ __align__(16) f16 Bb[2][256*64];

  const int tid = threadIdx.x;
  const int l   = tid & 63;
  const int w   = tid >> 6;          // 0..7
  const int wr  = w >> 2;            // 0..1 (M half)
  const int wc  = w & 3;             // 0..3 (N quarter)
  const int lr  = l & 15;
  const int lk  = l >> 4;
  const int e7  = lr & 7;

  // XCD-aware block swizzle (all grids have nwg % 8 == 0)
  const int nbx = gridDim.x;
  int id = blockIdx.y * nbx + blockIdx.x;
  const int nwg = nbx * (int)gridDim.y;
  id = (id & 7) * (nwg >> 3) + (id >> 3);
  const int bn = (id % nbx) * 256;
  const int bm = (id / nbx) * 256;

  const int nt = K >> 6;             // K-tiles of 64

  // staging: per wave-issue, 64 lanes x 16B = 8 rows x 128B. lane l -> local row
  // (l>>3), phys chunk (l&7). Global source pre-swizzled: logical chunk = (l&7)^(l>>3).
  const int srow = w*8 + (l >> 3);
  const int scl  = (l & 7) ^ (l >> 3);
  const f16* Ag = A + (size_t)(bm + srow) * K + scl*8;
  const f16* Bg = B + (size_t)(bn + srow) * K + scl*8;

#define STG(dst, src, h, kt) \
    gl_lds16((src) + (size_t)((h)*128   )*K + (kt)*64, &(dst)[(((h)*128      + w*8))*64]); \
    gl_lds16((src) + (size_t)((h)*128+64)*K + (kt)*64, &(dst)[(((h)*128 + 64 + w*8))*64]);

  // read-side: logical (row r, chunk c) lives at phys chunk c^(r&7); r&7 == lr&7
  const int arb = (wr*128 + lr)*64;
  const int brb = (wc*64  + lr)*64;
  const int cx0 = ((lk    ) ^ e7) << 3;   // kk=0 chunk, elements
  const int cx1 = ((lk + 4) ^ e7) << 3;   // kk=1 chunk

  f32x4 acc[8][4];
#pragma unroll
  for (int m = 0; m < 8; ++m)
#pragma unroll
    for (int n = 0; n < 4; ++n)
      acc[m][n] = (f32x4){0.f, 0.f, 0.f, 0.f};

  // prologue: tile0 -> buf0 (A+B, 8 issues), tile1 B -> buf1 (4 issues)
  STG(Ab[0], Ag, 0, 0) STG(Ab[0], Ag, 1, 0)
  STG(Bb[0], Bg, 0, 0) STG(Bb[0], Bg, 1, 0)
  STG(Bb[1], Bg, 0, 1) STG(Bb[1], Bg, 1, 1)
  asm volatile("s_waitcnt vmcnt(4)" ::: "memory");   // tile0 landed
  __builtin_amdgcn_s_barrier();

  f16x8 a0[4][2], a1[4][2], b0[2][2], b1[2][2];

  for (int t = 0; t < nt; ++t) {
    const int cur = t & 1;
    const f16* Ac = Ab[cur];
    const f16* Bc = Bb[cur];
    f16* An = Ab[cur ^ 1];
    f16* Bs = Bb[cur];
    const int ta = (t+1 < nt) ? (t+1) : (nt-1);   // clamped prefetch (dup, never read)
    const int tb = (t+2 < nt) ? (t+2) : (nt-1);

    // ---- phase a: Q0 (m0-3 x n0-1). reads: A m0-3, B n0-1 (12). stage A[t+1].h0
#pragma unroll
    for (int m = 0; m < 4; ++m) {
      a0[m][0] = *(const f16x8*)&Ac[arb + m*1024 + cx0];
      a0[m][1] = *(const f16x8*)&Ac[arb + m*1024 + cx1];
    }
#pragma unroll
    for (int n = 0; n < 2; ++n) {
      b0[n][0] = *(const f16x8*)&Bc[brb + n*1024 + cx0];
      b0[n][1] = *(const f16x8*)&Bc[brb + n*1024 + cx1];
    }
    STG(An, Ag, 0, ta)
    __builtin_amdgcn_s_barrier();
    asm volatile("s_waitcnt lgkmcnt(0)" ::: "memory");
    __builtin_amdgcn_sched_barrier(0);
    __builtin_amdgcn_s_setprio(1);
#pragma unroll
    for (int m = 0; m < 4; ++m)
#pragma unroll
      for (int n = 0; n < 2; ++n) {
        acc[m][n] = __builtin_amdgcn_mfma_f32_16x16x32_f16(a0[m][0], b0[n][0], acc[m][n], 0,0,0);
        acc[m][n] = __builtin_amdgcn_mfma_f32_16x16x32_f16(a0[m][1], b0[n][1], acc[m][n], 0,0,0);
      }
    __builtin_amdgcn_s_setprio(0);
    __builtin_amdgcn_s_barrier();

    // ---- phase b: Q1 (m0-3 x n2-3). reads: B n2-3 (4). stage A[t+1].h1
#pragma unroll
    for (int n = 0; n < 2; ++n) {
      b1[n][0] = *(const f16x8*)&Bc[brb + (n+2)*1024 + cx0];
      b1[n][1] = *(const f16x8*)&Bc[brb + (n+2)*1024 + cx1];
    }
    STG(An, Ag, 1, ta)
    __builtin_amdgcn_s_barrier();
    asm volatile("s_waitcnt lgkmcnt(0)" ::: "memory");
    __builtin_amdgcn_sched_barrier(0);
    __builtin_amdgcn_s_setprio(1);
#pragma unroll
    for (int m = 0; m < 4; ++m)
#pragma unroll
      for (int n = 0; n < 2; ++n) {
        acc[m][n+2] = __builtin_amdgcn_mfma_f32_16x16x32_f16(a0[m][0], b1[n][0], acc[m][n+2], 0,0,0);
        acc[m][n+2] = __builtin_amdgcn_mfma_f32_16x16x32_f16(a0[m][1], b1[n][1], acc[m][n+2], 0,0,0);
      }
    __builtin_amdgcn_s_setprio(0);
    __builtin_amdgcn_s_barrier();

    // ---- phase c: Q2 (m4-7 x n0-1). reads: A m4-7 (8). stage B[t+2].h0 (buf cur: B fully read)
#pragma unroll
    for (int m = 0; m < 4; ++m) {
      a1[m][0] = *(const f16x8*)&Ac[arb + (m+4)*1024 + cx0];
      a1[m][1] = *(const f16x8*)&Ac[arb + (m+4)*1024 + cx1];
    }
    STG(Bs, Bg, 0, tb)
    __builtin_amdgcn_s_barrier();
    asm volatile("s_waitcnt lgkmcnt(0)" ::: "memory");
    __builtin_amdgcn_sched_barrier(0);
    __builtin_amdgcn_s_setprio(1);
#pragma unroll
    for (int m = 0; m < 4; ++m)
#pragma unroll
      for (int n = 0; n < 2; ++n) {
        acc[m+4][n] = __builtin_amdgcn_mfma_f32_16x16x32_f16(a1[m][0], b0[n][0], acc[m+4][n], 0,0,0);
        acc[m+4][n] = __builtin_amdgcn_mfma_f32_16x16x32_f16(a1[m][1], b0[n][1], acc[m+4][n], 0,0,0);
      }
    __builtin_amdgcn_s_setprio(0);
    __builtin_amdgcn_s_barrier();

    // ---- phase d: Q3 (m4-7 x n2-3). no reads. stage B[t+2].h1, then vmcnt gate:
    // outstanding = this half's 8 + prev half's 4 -> vmcnt(4) retires tile t+1 fully.
    STG(Bs, Bg, 1, tb)
    asm volatile("s_waitcnt vmcnt(4)" ::: "memory");
    __builtin_amdgcn_s_barrier();
    __builtin_amdgcn_s_setprio(1);
#pragma unroll
    for (int m = 0; m < 4; ++m)
#pragma unroll
      for (int n = 0; n < 2; ++n) {
        acc[m+4][n+2] = __builtin_amdgcn_mfma_f32_16x16x32_f16(a1[m][0], b1[n][0], acc[m+4][n+2], 0,0,0);
        acc[m+4][n+2] = __builtin_amdgcn_mfma_f32_16x16x32_f16(a1[m][1], b1[n][1], acc[m+4][n+2], 0,0,0);
      }
    __builtin_amdgcn_s_setprio(0);
    __builtin_amdgcn_s_barrier();
  }
#undef STG

  asm volatile("s_waitcnt vmcnt(0)" ::: "memory");

  // epilogue: frag C/D layout col = lane&15, row = (lane>>4)*4 + i
  const int row0 = bm + wr*128 + lk*4;
  const int col0 = bn + wc*64 + lr;
#pragma unroll
  for (int m = 0; m < 8; ++m) {
#pragma unroll
    for (int n = 0; n < 4; ++n) {
      const int c = col0 + n*16;
#pragma unroll
      for (int i = 0; i < 4; ++i) {
        const int r = row0 + m*16 + i;
        const float v = acc[m][n][i];
        if (MODE == 0) {
          if (c < 2048) {
            out0[(size_t)r*2048 + c] = v;
          } else {
            float sg = 1.f / (1.f + __expf(-v));
            out1[(size_t)r*2048 + (c - 2048)] = (f16)(v * sg);
          }
        } else if (MODE == 1) {
          if (c < 2048) {
            float tt = v + bias[c];
            out0[(size_t)r*2048 + c] = (tt > 15.f) ? tt : log1pf(__expf(tt));
          } else if (c < 2080) {
            out0b[(size_t)r*32 + (c - 2048)] = v;
          }
        } else {
          out0[(size_t)r*N + c] = v;
        }
      }
    }
  }
}

// ---------------------------------------------------------------- conv+silu
// 4 timesteps per thread: 7 row-reads for 4 outputs (vs 16).
__global__ __launch_bounds__(256)
void conv_silu4(const float* __restrict__ xin, const float* __restrict__ cw,
                const float* __restrict__ cb, f16* __restrict__ xc)
{
  const int idx = blockIdx.x * 256 + threadIdx.x;    // 4,194,304 total
  const int d  = idx & (INNER_ - 1);
  const int g  = idx >> 11;
  const int t0 = (g & 511) << 2;
  const int b  = g >> 9;
  const size_t rbase = ((size_t)b*LSEQ_ + t0)*INNER_ + d;

  const float w0 = cw[d*4], w1 = cw[d*4+1], w2 = cw[d*4+2], w3 = cw[d*4+3];
  const float bs = cb[d];
  float xm3 = 0.f, xm2 = 0.f, xm1 = 0.f;
  if (t0) {
    xm3 = xin[rbase - 3*INNER_];
    xm2 = xin[rbase - 2*INNER_];
    xm1 = xin[rbase - 1*INNER_];
  }
  const float x0 = xin[rbase];
  const float x1 = xin[rbase + INNER_];
  const float x2 = xin[rbase + 2*INNER_];
  const float x3 = xin[rbase + 3*INNER_];

  float c0 = bs + w0*xm3 + w1*xm2 + w2*xm1 + w3*x0;
  float c1 = bs + w0*xm2 + w1*xm1 + w2*x0  + w3*x1;
  float c2 = bs + w0*xm1 + w1*x0  + w2*x1  + w3*x2;
  float c3 = bs + w0*x0  + w1*x1  + w2*x2  + w3*x3;

  xc[rbase            ] = (f16)(c0 / (1.f + __expf(-c0)));
  xc[rbase +   INNER_ ] = (f16)(c1 / (1.f + __expf(-c1)));
  xc[rbase + 2*INNER_ ] = (f16)(c2 / (1.f + __expf(-c2)));
  xc[rbase + 3*INNER_ ] = (f16)(c3 / (1.f + __expf(-c3)));
}

// ---------------------------------------------------------------- scan
__global__ __launch_bounds__(256)
void scan_local(const float* __restrict__ dt, const f16* __restrict__ xc,
                const float* __restrict__ bc32, const float* __restrict__ alog,
                float* __restrict__ Q, float* __restrict__ DTS)
{
  const int tid = threadIdx.x;
  const int b = blockIdx.z, seg = blockIdx.y, dc = blockIdx.x;
  const int d = dc*256 + tid;
  const int r0 = b*LSEQ_ + seg*SEGLEN_;

  __shared__ float bs[SEGLEN_][16];
  for (int i = tid; i < SEGLEN_*16; i += 256)
    bs[i >> 4][i & 15] = bc32[(size_t)(r0 + (i >> 4))*32 + (i & 15)];

  float Ac[16];
#pragma unroll
  for (int s = 0; s < 16; ++s) Ac[s] = -__expf(alog[d*16 + s]);
  __syncthreads();

  float st[16];
#pragma unroll
  for (int s = 0; s < 16; ++s) st[s] = 0.f;
  float dtsum = 0.f;

  for (int tt = 0; tt < SEGLEN_; ++tt) {
    const size_t idx = (size_t)(r0 + tt)*INNER_ + d;
    const float dtv = dt[idx];
    const float xv  = (float)xc[idx];
    const float dtx = dtv * xv;
    dtsum += dtv;
#pragma unroll
    for (int s = 0; s < 16; ++s) {
      float ab = __expf(Ac[s]*dtv);
      st[s] = fmaf(ab, st[s], dtx * bs[tt][s]);
    }
  }
  const size_t qb = ((size_t)(b*INNER_ + d)*SEG_ + seg)*16;
#pragma unroll
  for (int s = 0; s < 16; ++s) Q[qb + s] = st[s];
  DTS[(size_t)(b*INNER_ + d)*SEG_ + seg] = dtsum;
}

// segment-level scan; QI is Q on input, INIT on output (in-place, read-before-write)
__global__ __launch_bounds__(256)
void scan_fix(const float* __restrict__ alog, const float* __restrict__ DTS,
              float* __restrict__ QI)
{
  const int idx = blockIdx.x*256 + threadIdx.x;
  const int s = idx & 15;
  const int bd = idx >> 4;
  const int d = bd & (INNER_ - 1);
  const float A = -__expf(alog[d*16 + s]);
  float st = 0.f;
  for (int seg = 0; seg < SEG_; ++seg) {
    const size_t base = ((size_t)bd*SEG_ + seg)*16 + s;
    const float q = QI[base];
    const float dts = DTS[(size_t)bd*SEG_ + seg];
    QI[base] = st;
    st = __expf(A*dts)*st + q;
  }
}

__global__ __launch_bounds__(256)
void scan_final(const float* __restrict__ dt, const f16* __restrict__ xc,
                const float* __restrict__ bc32, const float* __restrict__ alog,
                const float* __restrict__ INIT, const f16* __restrict__ res,
                f16* __restrict__ y16)
{
  const int tid = threadIdx.x;
  const int b = blockIdx.z, seg = blockIdx.y, dc = blockIdx.x;
  const int d = dc*256 + tid;
  const int r0 = b*LSEQ_ + seg*SEGLEN_;

  __shared__ float bs[SEGLEN_][32];
  for (int i = tid; i < SEGLEN_*32; i += 256)
    bs[i >> 5][i & 31] = bc32[(size_t)(r0 + (i >> 5))*32 + (i & 31)];

  float Ac[16];
#pragma unroll
  for (int s = 0; s < 16; ++s) Ac[s] = -__expf(alog[d*16 + s]);

  float st[16];
  const size_t ib = ((size_t)(b*INNER_ + d)*SEG_ + seg)*16;
#pragma unroll
  for (int s = 0; s < 16; ++s) st[s] = INIT[ib + s];
  __syncthreads();

  for (int tt = 0; tt < SEGLEN_; ++tt) {
    const size_t idx = (size_t)(r0 + tt)*INNER_ + d;
    const float dtv = dt[idx];
    const float xv  = (float)xc[idx];
    const float dtx = dtv * xv;
    float y = 0.f;
#pragma unroll
    for (int s = 0; s < 16; ++s) {
      float ab = __expf(Ac[s]*dtv);
      st[s] = fmaf(ab, st[s], dtx * bs[tt][s]);
      y = fmaf(st[s], bs[tt][16 + s], y);
    }
    y16[idx] = (f16)(y * (float)res[idx]);
  }
}

// ---------------------------------------------------------------- launch
extern "C" void kernel_launch(void* const* d_in, const int* in_sizes, int n_in,
                              void* d_out, int out_size, void* d_ws, size_t ws_size,
                              hipStream_t stream)
{
  const float* x    = (const float*)d_in[0];
  const float* w1   = (const float*)d_in[1];
  const float* cw   = (const float*)d_in[2];
  const float* cb   = (const float*)d_in[3];
  const float* dtw  = (const float*)d_in[4];
  const float* dtb  = (const float*)d_in[5];
  const float* alog = (const float*)d_in[6];
  const float* bw   = (const float*)d_in[7];
  const float* cwt  = (const float*)d_in[8];
  const float* ow   = (const float*)d_in[9];
  float* out = (float*)d_out;

  char* ws = (char*)d_ws;
  // workspace layout (bytes), total ~216.5 MB
  f16*   X16   = (f16*)  (ws + 0);          // 8192x1024 f16   = 16777216
  f16*   W1_16 = (f16*)  (ws + 16777216);   // 4096x1024 f16   =  8388608
  f16*   W2_16 = (f16*)  (ws + 25165824);   // 2304x2048 f16   =  9437184 (N padded)
  f16*   OW16  = (f16*)  (ws + 34603008);   // 1024x2048 f16   =  4194304
  f16*   RES16 = (f16*)  (ws + 38797312);   // 8192x2048 f16   = 33554432 (silu(res))
  f16*   XC16  = (f16*)  (ws + 72351744);   // 8192x2048 f16   = 33554432
  float* XIN32 = (float*)(ws + 105906176);  // 8192x2048 f32   = 67108864
  float* DT32  = XIN32;                     // aliased: XIN32 dead after conv
  float* BC32  = (float*)(ws + 173015040);  // 8192x32 f32     =  1048576
  float* DTS   = (float*)(ws + 174063616);  // 8192x16 f32     =   524288
  float* Q     = (float*)(ws + 174587904);  // 8192x16x16 f32  =  8388608 (also INIT)
  f16*   Y16   = (f16*)  (ws + 182976512);  // 8192x2048 f16   = 33554432

  cvt16<<<2048, 256, 0, stream>>>(x,   X16,   NROWS_*DIM_);
  cvt16<<<2048, 256, 0, stream>>>(w1,  W1_16, 2*INNER_*DIM_);
  cvt16<<<2048, 256, 0, stream>>>(dtw, W2_16, INNER_*INNER_);
  cvt16<<<64,   256, 0, stream>>>(bw,  W2_16 + (size_t)2048*2048, STATE_*INNER_);
  cvt16<<<64,   256, 0, stream>>>(cwt, W2_16 + (size_t)2064*2048, STATE_*INNER_);
  fillz16<<<1792, 256, 0, stream>>>(W2_16 + (size_t)2080*2048, 224*2048);
  cvt16<<<2048, 256, 0, stream>>>(ow,  OW16,  DIM_*INNER_);

  // GEMM1: xr = x @ in_proj_w^T -> x_in fp32, silu(res) f16
  gemm8p<0><<<dim3(16, 32), 512, 0, stream>>>(X16, W1_16, NROWS_, 4096, 1024,
                                              XIN32, nullptr, RES16, nullptr);
  // depthwise conv + silu
  conv_silu4<<<16384, 256, 0, stream>>>(XIN32, cw, cb, XC16);
  // GEMM2: dt (+bias, softplus) and Bm/Cm (extra cols, N padded to 2304)
  gemm8p<1><<<dim3(9, 32), 512, 0, stream>>>(XC16, W2_16, NROWS_, 2304, 2048,
                                             DT32, BC32, nullptr, dtb);
  // segmented selective scan
  scan_local<<<dim3(8, SEG_, BATCH_), 256, 0, stream>>>(DT32, XC16, BC32, alog, Q, DTS);
  scan_fix  <<<512, 256, 0, stream>>>(alog, DTS, Q);
  scan_final<<<dim3(8, SEG_, BATCH_), 256, 0, stream>>>(DT32, XC16, BC32, alog, Q, RES16, Y16);
  // GEMM3: out = (y * silu(res)) @ out_w^T
  gemm8p<2><<<dim3(4, 32), 512, 0, stream>>>(Y16, OW16, NROWS_, 1024, 2048,
                                             out, nullptr, nullptr, nullptr);
}

// Round 3
// 513.729 us; speedup vs baseline: 1.2313x; 1.1407x over previous
//
#include <hip/hip_runtime.h>
#include <hip/hip_fp16.h>
#include <stdint.h>
#include <math.h>

typedef _Float16 f16;
typedef _Float16 f16x8 __attribute__((ext_vector_type(8)));
typedef float f32x4 __attribute__((ext_vector_type(4)));

#define DIM_   1024
#define STATE_ 16
#define INNER_ 2048
#define BATCH_ 4
#define LSEQ_  2048
#define NROWS_ 8192
#define SEG_   16
#define SEGLEN_ 128

// ---------------------------------------------------------------- utilities
__device__ __forceinline__ void gl_lds16(const void* g, void* l) {
  __builtin_amdgcn_global_load_lds(
      (const __attribute__((address_space(1))) uint32_t*)g,
      (__attribute__((address_space(3))) uint32_t*)l,
      16, 0, 0);
}

__global__ void cvt16(const float* __restrict__ in, f16* __restrict__ out, int n) {
  int i = blockIdx.x * 256 + threadIdx.x;
  int stride = gridDim.x * 256;
  for (; i < n; i += stride) out[i] = (f16)in[i];
}

// ---------------------------------------------------------------- GEMM (pipelined)
// C[M,N] = A[M,K] @ B[N,K]^T, f16 in, f32 acc, MFMA 16x16x32.
// Tile BM x 256, BK=64, 8 waves (2M x 4N), per-wave (BM/2) x 64.
// 2 barriers per K-tile; reads of next phase overlap MFMA of current phase;
// A[t+2]/B[t+2] staged at phase2 of iter t, gated (counted vmcnt) at phase3 of
// iter t+1 -> a full iteration of latency cover. XOR chunk swizzle on LDS
// (pre-swizzled global source), XCD block swizzle, setprio around MFMA.
template<int MODE, int BM>
__global__ __launch_bounds__(512, 2)
void gemm_pipe(const f16* __restrict__ A, const f16* __restrict__ B,
               int M, int N, int K,
               float* __restrict__ out0, f16* __restrict__ out1,
               f16* __restrict__ out1b, const float* __restrict__ bias)
{
  constexpr int MF = BM / 32;     // m-frags per wave
  constexpr int MH = MF / 2;
  constexpr int AL = BM / 64;     // A stage issues per K-tile (per wave)
  constexpr int GATE = AL + 4;    // loads per K-tile per wave

  __shared__ __align__(16) f16 Ab[2][BM * 64];
  __shared__ __align__(16) f16 Bb[2][256 * 64];

  const int tid = threadIdx.x;
  const int l   = tid & 63;
  const int w   = tid >> 6;          // 0..7
  const int wr  = w >> 2;            // 0..1
  const int wc  = w & 3;             // 0..3
  const int lr  = l & 15;
  const int lk  = l >> 4;
  const int e7  = lr & 7;

  // XCD-aware swizzle (grids are multiples of 8)
  const int nbx = gridDim.x;
  int id = blockIdx.y * nbx + blockIdx.x;
  const int nwg = nbx * (int)gridDim.y;
  id = (id & 7) * (nwg >> 3) + (id >> 3);
  const int bn = (id % nbx) * 256;
  const int bm = (id / nbx) * BM;

  const int nt = K >> 6;             // K-tiles (even for all our shapes)

  // staging: one gl_lds16 per wave covers 8 rows x 128B. lane -> local row l>>3,
  // phys chunk l&7; source pre-swizzled: logical chunk = (l&7)^(l>>3).
  const int srow = w*8 + (l >> 3);
  const int scl  = (l & 7) ^ (l >> 3);
  const f16* Ag = A + (size_t)(bm + srow) * K + scl*8;
  const f16* Bg = B + (size_t)(bn + srow) * K + scl*8;

#define STGA(DST, KT) _Pragma("unroll") for (int j = 0; j < AL; ++j) \
    gl_lds16(Ag + (size_t)(j*64)*K + (size_t)(KT)*64, (void*)&(DST)[(j*64 + w*8)*64]);
#define STGB(DST, KT) _Pragma("unroll") for (int j = 0; j < 4; ++j) \
    gl_lds16(Bg + (size_t)(j*64)*K + (size_t)(KT)*64, (void*)&(DST)[(j*64 + w*8)*64]);

  const int arb = (wr*(BM/2) + lr)*64;
  const int brb = (wc*64 + lr)*64;
  const int cx0 = ((lk    ) ^ e7) << 3;
  const int cx1 = ((lk + 4) ^ e7) << 3;

  f32x4 acc[MF][4];
#pragma unroll
  for (int m = 0; m < MF; ++m)
#pragma unroll
    for (int n = 0; n < 4; ++n) acc[m][n] = (f32x4){0.f,0.f,0.f,0.f};

  f16x8 a0[MH][2], a1[MH][2], b0[2][2], b1[2][2];

#define LDA0(BUF) _Pragma("unroll") for (int m = 0; m < MH; ++m) { \
    a0[m][0] = *(const f16x8*)&(BUF)[arb + m*1024 + cx0]; \
    a0[m][1] = *(const f16x8*)&(BUF)[arb + m*1024 + cx1]; }
#define LDA1(BUF) _Pragma("unroll") for (int m = 0; m < MH; ++m) { \
    a1[m][0] = *(const f16x8*)&(BUF)[arb + (m+MH)*1024 + cx0]; \
    a1[m][1] = *(const f16x8*)&(BUF)[arb + (m+MH)*1024 + cx1]; }
#define LDB0(BUF) _Pragma("unroll") for (int n = 0; n < 2; ++n) { \
    b0[n][0] = *(const f16x8*)&(BUF)[brb + n*1024 + cx0]; \
    b0[n][1] = *(const f16x8*)&(BUF)[brb + n*1024 + cx1]; }
#define LDB1(BUF) _Pragma("unroll") for (int n = 0; n < 2; ++n) { \
    b1[n][0] = *(const f16x8*)&(BUF)[brb + (n+2)*1024 + cx0]; \
    b1[n][1] = *(const f16x8*)&(BUF)[brb + (n+2)*1024 + cx1]; }

#define MM(AC, AV, BV) AC = __builtin_amdgcn_mfma_f32_16x16x32_f16(AV, BV, AC, 0, 0, 0)
#define M0_ _Pragma("unroll") for (int m = 0; m < MH; ++m) _Pragma("unroll") for (int n = 0; n < 2; ++n) { \
    MM(acc[m][n], a0[m][0], b0[n][0]); MM(acc[m][n], a0[m][1], b0[n][1]); }
#define M1_ _Pragma("unroll") for (int m = 0; m < MH; ++m) _Pragma("unroll") for (int n = 0; n < 2; ++n) { \
    MM(acc[m][n+2], a0[m][0], b1[n][0]); MM(acc[m][n+2], a0[m][1], b1[n][1]); }
#define M2_ _Pragma("unroll") for (int m = 0; m < MH; ++m) _Pragma("unroll") for (int n = 0; n < 2; ++n) { \
    MM(acc[m+MH][n], a1[m][0], b0[n][0]); MM(acc[m+MH][n], a1[m][1], b0[n][1]); }
#define M3_ _Pragma("unroll") for (int m = 0; m < MH; ++m) _Pragma("unroll") for (int n = 0; n < 2; ++n) { \
    MM(acc[m+MH][n+2], a1[m][0], b1[n][0]); MM(acc[m+MH][n+2], a1[m][1], b1[n][1]); }

#define GATEW do { if constexpr (GATE == 8) asm volatile("s_waitcnt vmcnt(8)" ::: "memory"); \
                   else asm volatile("s_waitcnt vmcnt(6)" ::: "memory"); } while (0)
#define PR1 __builtin_amdgcn_s_setprio(1)
#define PR0 __builtin_amdgcn_s_setprio(0)

  // prologue: tiles 0,1 staged; gate tile0; issue its a0/b0 reads
  STGA(Ab[0], 0) STGB(Bb[0], 0)
  STGA(Ab[1], 1) STGB(Bb[1], 1)
  GATEW;
  __builtin_amdgcn_s_barrier();
  LDA0(Ab[0]) LDB0(Bb[0])

#define ITER(CUR, T) { \
    const int tb = ((T)+2 < nt) ? (T)+2 : nt-1; \
    /* p0: overlap b1 reads with M0 */ \
    LDB1(Bb[CUR]) \
    PR1; M0_ PR0; \
    /* p1: overlap a1 reads with M1; then drain reads + barrier (write-after-read fence) */ \
    LDA1(Ab[CUR]) \
    PR1; M1_ PR0; \
    asm volatile("s_waitcnt lgkmcnt(0)" ::: "memory"); \
    __builtin_amdgcn_s_barrier(); \
    /* p2: stage tile T+2 into the fully-read current buffers; overlap with M2 */ \
    STGA(Ab[CUR], tb) STGB(Bb[CUR], tb) \
    PR1; M2_ PR0; \
    /* p3: gate tile T+1 (staged last iter), then issue next-iter a0/b0 under M3 */ \
    GATEW; \
    __builtin_amdgcn_s_barrier(); \
    LDA0(Ab[CUR^1]) LDB0(Bb[CUR^1]) \
    PR1; M3_ PR0; \
  }

  for (int t = 0; t < nt; t += 2) {
    ITER(0, t)
    ITER(1, t+1)
  }
#undef ITER

  asm volatile("s_waitcnt vmcnt(0)" ::: "memory");

  // epilogue: C/D frag layout col = lane&15, row = (lane>>4)*4 + i
  const int row0 = bm + wr*(BM/2) + lk*4;
  const int col0 = bn + wc*64 + lr;
#pragma unroll
  for (int m = 0; m < MF; ++m) {
#pragma unroll
    for (int n = 0; n < 4; ++n) {
      const int c = col0 + n*16;
#pragma unroll
      for (int i = 0; i < 4; ++i) {
        const int r = row0 + m*16 + i;
        const float v = acc[m][n][i];
        if (MODE == 0) {                      // in_proj: x_in f16 | silu(res) f16
          if (c < 2048) {
            out1[(size_t)r*2048 + c] = (f16)v;
          } else {
            float sg = 1.f / (1.f + __expf(-v));
            out1b[(size_t)r*2048 + (c - 2048)] = (f16)(v * sg);
          }
        } else if (MODE == 1) {               // dt: softplus(v + bias)
          float tt = v + bias[c];
          out0[(size_t)r*2048 + c] = (tt > 15.f) ? tt : log1pf(__expf(tt));
        } else {
          out0[(size_t)r*N + c] = v;
        }
      }
    }
  }
#undef STGA
#undef STGB
#undef LDA0
#undef LDA1
#undef LDB0
#undef LDB1
#undef MM
#undef M0_
#undef M1_
#undef M2_
#undef M3_
#undef GATEW
#undef PR1
#undef PR0
}

// ---------------------------------------------------------------- Bm/Cm skinny GEMM
// outBC[r][0..31] = xc_row . W[s]  (W = [B_w;C_w] as f16 [32][2048]).
// Block: 128 rows x 32 cols, 4 waves, BK=64, simple 2-barrier loop.
__global__ __launch_bounds__(256)
void gemm_bc(const f16* __restrict__ A, const f16* __restrict__ W,
             float* __restrict__ outBC)
{
  __shared__ __align__(16) f16 Xs[128*72];
  __shared__ __align__(16) f16 Ws[32*72];
  const int tid = threadIdx.x;
  const int l = tid & 63, w = tid >> 6;
  const int lr = l & 15, lk = l >> 4;
  const int bm = blockIdx.x * 128;

  f32x4 acc[2][2];
#pragma unroll
  for (int m = 0; m < 2; ++m)
#pragma unroll
    for (int n = 0; n < 2; ++n) acc[m][n] = (f32x4){0.f,0.f,0.f,0.f};

  for (int k0 = 0; k0 < 2048; k0 += 64) {
#pragma unroll
    for (int c = 0; c < 4; ++c) {
      int u = tid + c*256;                       // f16x8 unit over 128x64 tile
      int row = u >> 3, k8 = u & 7;
      *(f16x8*)&Xs[row*72 + k8*8] =
          *(const f16x8*)&A[(size_t)(bm + row)*2048 + k0 + k8*8];
    }
    { int row = tid >> 3, k8 = tid & 7;          // 32x64 tile
      *(f16x8*)&Ws[row*72 + k8*8] =
          *(const f16x8*)&W[(size_t)row*2048 + k0 + k8*8]; }
    __syncthreads();
#pragma unroll
    for (int kk = 0; kk < 2; ++kk) {
      f16x8 x0 = *(const f16x8*)&Xs[(w*32      + lr)*72 + kk*32 + lk*8];
      f16x8 x1 = *(const f16x8*)&Xs[(w*32 + 16 + lr)*72 + kk*32 + lk*8];
      f16x8 w0 = *(const f16x8*)&Ws[(lr     )*72 + kk*32 + lk*8];
      f16x8 w1 = *(const f16x8*)&Ws[(16 + lr)*72 + kk*32 + lk*8];
      acc[0][0] = __builtin_amdgcn_mfma_f32_16x16x32_f16(x0, w0, acc[0][0], 0,0,0);
      acc[0][1] = __builtin_amdgcn_mfma_f32_16x16x32_f16(x0, w1, acc[0][1], 0,0,0);
      acc[1][0] = __builtin_amdgcn_mfma_f32_16x16x32_f16(x1, w0, acc[1][0], 0,0,0);
      acc[1][1] = __builtin_amdgcn_mfma_f32_16x16x32_f16(x1, w1, acc[1][1], 0,0,0);
    }
    __syncthreads();
  }
#pragma unroll
  for (int m = 0; m < 2; ++m)
#pragma unroll
    for (int n = 0; n < 2; ++n)
#pragma unroll
      for (int i = 0; i < 4; ++i) {
        int row = bm + w*32 + m*16 + lk*4 + i;
        int col = n*16 + lr;
        outBC[(size_t)row*32 + col] = acc[m][n][i];
      }
}

// ---------------------------------------------------------------- conv+silu
// 4 timesteps/thread; input x_in f16, output xc f16.
__global__ __launch_bounds__(256)
void conv_silu4(const f16* __restrict__ xin, const float* __restrict__ cw,
                const float* __restrict__ cb, f16* __restrict__ xc)
{
  const int idx = blockIdx.x * 256 + threadIdx.x;
  const int d  = idx & (INNER_ - 1);
  const int g  = idx >> 11;
  const int t0 = (g & 511) << 2;
  const int b  = g >> 9;
  const size_t rbase = ((size_t)b*LSEQ_ + t0)*INNER_ + d;

  const float w0 = cw[d*4], w1 = cw[d*4+1], w2 = cw[d*4+2], w3 = cw[d*4+3];
  const float bs = cb[d];
  float xm3 = 0.f, xm2 = 0.f, xm1 = 0.f;
  if (t0) {
    xm3 = (float)xin[rbase - 3*INNER_];
    xm2 = (float)xin[rbase - 2*INNER_];
    xm1 = (float)xin[rbase - 1*INNER_];
  }
  const float x0 = (float)xin[rbase];
  const float x1 = (float)xin[rbase + INNER_];
  const float x2 = (float)xin[rbase + 2*INNER_];
  const float x3 = (float)xin[rbase + 3*INNER_];

  float c0 = bs + w0*xm3 + w1*xm2 + w2*xm1 + w3*x0;
  float c1 = bs + w0*xm2 + w1*xm1 + w2*x0  + w3*x1;
  float c2 = bs + w0*xm1 + w1*x0  + w2*x1  + w3*x2;
  float c3 = bs + w0*x0  + w1*x1  + w2*x2  + w3*x3;

  xc[rbase            ] = (f16)(c0 / (1.f + __expf(-c0)));
  xc[rbase +   INNER_ ] = (f16)(c1 / (1.f + __expf(-c1)));
  xc[rbase + 2*INNER_ ] = (f16)(c2 / (1.f + __expf(-c2)));
  xc[rbase + 3*INNER_ ] = (f16)(c3 / (1.f + __expf(-c3)));
}

// ---------------------------------------------------------------- scan
__global__ __launch_bounds__(256)
void scan_local(const float* __restrict__ dt, const f16* __restrict__ xc,
                const float* __restrict__ bc32, const float* __restrict__ alog,
                float* __restrict__ Q, float* __restrict__ DTS)
{
  const int tid = threadIdx.x;
  const int b = blockIdx.z, seg = blockIdx.y, dc = blockIdx.x;
  const int d = dc*256 + tid;
  const int r0 = b*LSEQ_ + seg*SEGLEN_;

  __shared__ float bs[SEGLEN_][16];
  for (int i = tid; i < SEGLEN_*16; i += 256)
    bs[i >> 4][i & 15] = bc32[(size_t)(r0 + (i >> 4))*32 + (i & 15)];

  float Ac[16];
#pragma unroll
  for (int s = 0; s < 16; ++s) Ac[s] = -__expf(alog[d*16 + s]);
  __syncthreads();

  float st[16];
#pragma unroll
  for (int s = 0; s < 16; ++s) st[s] = 0.f;
  float dtsum = 0.f;

  for (int tt = 0; tt < SEGLEN_; ++tt) {
    const size_t idx = (size_t)(r0 + tt)*INNER_ + d;
    const float dtv = dt[idx];
    const float xv  = (float)xc[idx];
    const float dtx = dtv * xv;
    dtsum += dtv;
#pragma unroll
    for (int s = 0; s < 16; ++s) {
      float ab = __expf(Ac[s]*dtv);
      st[s] = fmaf(ab, st[s], dtx * bs[tt][s]);
    }
  }
  const size_t qb = ((size_t)(b*INNER_ + d)*SEG_ + seg)*16;
#pragma unroll
  for (int s = 0; s < 16; ++s) Q[qb + s] = st[s];
  DTS[(size_t)(b*INNER_ + d)*SEG_ + seg] = dtsum;
}

// segment-level scan; QI = Q in, INIT out (in-place)
__global__ __launch_bounds__(256)
void scan_fix(const float* __restrict__ alog, const float* __restrict__ DTS,
              float* __restrict__ QI)
{
  const int idx = blockIdx.x*256 + threadIdx.x;
  const int s = idx & 15;
  const int bd = idx >> 4;
  const int d = bd & (INNER_ - 1);
  const float A = -__expf(alog[d*16 + s]);
  float st = 0.f;
  for (int seg = 0; seg < SEG_; ++seg) {
    const size_t base = ((size_t)bd*SEG_ + seg)*16 + s;
    const float q = QI[base];
    const float dts = DTS[(size_t)bd*SEG_ + seg];
    QI[base] = st;
    st = __expf(A*dts)*st + q;
  }
}

__global__ __launch_bounds__(256)
void scan_final(const float* __restrict__ dt, const f16* __restrict__ xc,
                const float* __restrict__ bc32, const float* __restrict__ alog,
                const float* __restrict__ INIT, const f16* __restrict__ res,
                f16* __restrict__ y16)
{
  const int tid = threadIdx.x;
  const int b = blockIdx.z, seg = blockIdx.y, dc = blockIdx.x;
  const int d = dc*256 + tid;
  const int r0 = b*LSEQ_ + seg*SEGLEN_;

  __shared__ float bs[SEGLEN_][32];
  for (int i = tid; i < SEGLEN_*32; i += 256)
    bs[i >> 5][i & 31] = bc32[(size_t)(r0 + (i >> 5))*32 + (i & 31)];

  float Ac[16];
#pragma unroll
  for (int s = 0; s < 16; ++s) Ac[s] = -__expf(alog[d*16 + s]);

  float st[16];
  const size_t ib = ((size_t)(b*INNER_ + d)*SEG_ + seg)*16;
#pragma unroll
  for (int s = 0; s < 16; ++s) st[s] = INIT[ib + s];
  __syncthreads();

  for (int tt = 0; tt < SEGLEN_; ++tt) {
    const size_t idx = (size_t)(r0 + tt)*INNER_ + d;
    const float dtv = dt[idx];
    const float xv  = (float)xc[idx];
    const float dtx = dtv * xv;
    float y = 0.f;
#pragma unroll
    for (int s = 0; s < 16; ++s) {
      float ab = __expf(Ac[s]*dtv);
      st[s] = fmaf(ab, st[s], dtx * bs[tt][s]);
      y = fmaf(st[s], bs[tt][16 + s], y);
    }
    y16[idx] = (f16)(y * (float)res[idx]);
  }
}

// ---------------------------------------------------------------- launch
extern "C" void kernel_launch(void* const* d_in, const int* in_sizes, int n_in,
                              void* d_out, int out_size, void* d_ws, size_t ws_size,
                              hipStream_t stream)
{
  const float* x    = (const float*)d_in[0];
  const float* w1   = (const float*)d_in[1];
  const float* cw   = (const float*)d_in[2];
  const float* cb   = (const float*)d_in[3];
  const float* dtw  = (const float*)d_in[4];
  const float* dtb  = (const float*)d_in[5];
  const float* alog = (const float*)d_in[6];
  const float* bw   = (const float*)d_in[7];
  const float* cwt  = (const float*)d_in[8];
  const float* ow   = (const float*)d_in[9];
  float* out = (float*)d_out;

  char* ws = (char*)d_ws;
  // workspace layout (bytes), total ~215.6 MB
  f16*   X16   = (f16*)  (ws + 0);          // 8192x1024 f16
  f16*   W1_16 = (f16*)  (ws + 16777216);   // 4096x1024 f16
  f16*   W2_16 = (f16*)  (ws + 25165824);   // 2048x2048 f16
  f16*   BCW16 = (f16*)  (ws + 33554432);   // 32x2048 f16 (B_w;C_w)
  f16*   OW16  = (f16*)  (ws + 33685504);   // 1024x2048 f16
  f16*   RES16 = (f16*)  (ws + 37879808);   // 8192x2048 f16  silu(res)
  f16*   XC16  = (f16*)  (ws + 71434240);   // 8192x2048 f16  conv output
  f16*   XI16  = (f16*)  (ws + 104988672);  // 8192x2048 f16  x_in (pre-conv)
  f16*   Y16   = XI16;                      // aliased: XI16 dead after conv
  float* DT32  = (float*)(ws + 138543104);  // 8192x2048 f32
  float* BC32  = (float*)(ws + 205651968);  // 8192x32 f32
  float* DTS   = (float*)(ws + 206700544);  // 8192x16 f32
  float* Q     = (float*)(ws + 207224832);  // 8192x16x16 f32 (also INIT)

  cvt16<<<2048, 256, 0, stream>>>(x,   X16,   NROWS_*DIM_);
  cvt16<<<2048, 256, 0, stream>>>(w1,  W1_16, 2*INNER_*DIM_);
  cvt16<<<2048, 256, 0, stream>>>(dtw, W2_16, INNER_*INNER_);
  cvt16<<<64,   256, 0, stream>>>(bw,  BCW16, STATE_*INNER_);
  cvt16<<<64,   256, 0, stream>>>(cwt, BCW16 + (size_t)16*2048, STATE_*INNER_);
  cvt16<<<2048, 256, 0, stream>>>(ow,  OW16,  DIM_*INNER_);

  // GEMM1: xr = x @ in_proj_w^T -> x_in f16, silu(res) f16   (512 blocks = 2 rounds)
  gemm_pipe<0,256><<<dim3(16, 32), 512, 0, stream>>>(X16, W1_16, NROWS_, 4096, 1024,
                                                     nullptr, XI16, RES16, nullptr);
  // depthwise conv + silu
  conv_silu4<<<16384, 256, 0, stream>>>(XI16, cw, cb, XC16);
  // GEMM2: dt = softplus(xc @ dt_w^T + b)                    (256 blocks = 1 round)
  gemm_pipe<1,256><<<dim3(8, 32), 512, 0, stream>>>(XC16, W2_16, NROWS_, 2048, 2048,
                                                    DT32, nullptr, nullptr, dtb);
  // Bm/Cm skinny GEMM (64 blocks)
  gemm_bc<<<64, 256, 0, stream>>>(XC16, BCW16, BC32);
  // segmented selective scan
  scan_local<<<dim3(8, SEG_, BATCH_), 256, 0, stream>>>(DT32, XC16, BC32, alog, Q, DTS);
  scan_fix  <<<512, 256, 0, stream>>>(alog, DTS, Q);
  scan_final<<<dim3(8, SEG_, BATCH_), 256, 0, stream>>>(DT32, XC16, BC32, alog, Q, RES16, Y16);
  // GEMM3: out = (y * silu(res)) @ out_w^T                   (BM=128 -> 256 blocks)
  gemm_pipe<2,128><<<dim3(4, 64), 512, 0, stream>>>(Y16, OW16, NROWS_, 1024, 2048,
                                                    out, nullptr, nullptr, nullptr);
}